// Round 7
// baseline (536.907 us; speedup 1.0000x reference)
//
#include <hip/hip_runtime.h>
#include <stdint.h>

#pragma clang fp contract(off)

#define NN 1024
#define BB 2048
#define ENS 1000
#define KK 32

#define NEGC -1.0e9f
#define PADV -1.0e10f
#define L2E 1.44269504088896341f

// ===================== XLA:CPU float32 math replicas (exact path) =====================
__device__ __forceinline__ float xla_expf(float xin) {
  float x = fminf(xin, 88.3762626647950f);
  x = fmaxf(x, -88.3762626647949f);
  float fx = floorf(__builtin_fmaf(x, 1.44269504088896341f, 0.5f));
  x = __builtin_fmaf(fx, -0.693359375f, x);
  x = __builtin_fmaf(fx, 2.12194440e-4f, x);
  float z = x * x;
  float y = 1.9875691500e-4f;
  y = __builtin_fmaf(y, x, 1.3981999507e-3f);
  y = __builtin_fmaf(y, x, 8.3334519073e-3f);
  y = __builtin_fmaf(y, x, 4.1665795894e-2f);
  y = __builtin_fmaf(y, x, 1.6666665459e-1f);
  y = __builtin_fmaf(y, x, 5.0000001201e-1f);
  y = __builtin_fmaf(y, z, x);
  y = y + 1.0f;
  int n = (int)fx;
  float two_n = __int_as_float((n + 127) << 23);
  return y * two_n;
}

__device__ __forceinline__ float xla_logf(float uin) {
  int ib = __float_as_int(uin);
  float e = (float)((ib >> 23) - 126);
  float m = __int_as_float((ib & 0x007FFFFF) | 0x3F000000);
  bool lt = m < 0.707106781186547524f;
  float tmp = lt ? m : 0.0f;
  e = lt ? (e - 1.0f) : e;
  float x = m - 1.0f;
  x = x + tmp;
  float z = x * x;
  float y = 7.0376836292e-2f;
  y = __builtin_fmaf(y, x, -1.1514610310e-1f);
  y = __builtin_fmaf(y, x, 1.1676998740e-1f);
  y = __builtin_fmaf(y, x, -1.2420140846e-1f);
  y = __builtin_fmaf(y, x, 1.4249322787e-1f);
  y = __builtin_fmaf(y, x, -1.6668057665e-1f);
  y = __builtin_fmaf(y, x, 2.0000714765e-1f);
  y = __builtin_fmaf(y, x, -2.4999993993e-1f);
  y = __builtin_fmaf(y, x, 3.3333331174e-1f);
  y = y * x;
  y = y * z;
  y = __builtin_fmaf(e, -2.12194440e-4f, y);
  y = __builtin_fmaf(z, -0.5f, y);
  x = x + y;
  x = __builtin_fmaf(e, 0.693359375f, x);
  return x;
}

__device__ __forceinline__ float xla_log1pf(float x) {
  float lg = xla_logf(x + 1.0f);
  float sm = __builtin_fmaf(-0.5f, x, 1.0f) * x;
  return (fabsf(x) < 1e-4f) ? sm : lg;
}

__device__ __forceinline__ float xla_logsigmoid(float v) {
  float y = -v;
  float amax = fmaxf(y, 0.0f);
  float sp = amax + xla_log1pf(xla_expf(-fabsf(y)));
  return -sp + 1e-7f;
}

// ===================== fast math (marginal path only; 2e-2 tolerance) ==============
__device__ __forceinline__ float fexp2(float x) { return __builtin_amdgcn_exp2f(x); }
__device__ __forceinline__ float flog2(float x) { return __builtin_amdgcn_logf(x); }

__device__ __forceinline__ float fast_lae(float a, float b) {
  float m = fmaxf(a, b);
  float d = -fabsf(a - b);
  float e = fexp2(d * L2E);
  return m + flog2(1.0f + e) * 0.69314718055994531f;
}

// ===================== DPP cross-lane helpers =====================
template <int CTRL, int ROWM>
__device__ __forceinline__ float dppz(float x) {
  return __int_as_float(__builtin_amdgcn_update_dpp(0, __float_as_int(x), CTRL, ROWM, 0xF, false));
}

__device__ __forceinline__ float shup1(float x) { return dppz<0x138, 0xF>(x); }  // wave_shr:1

// per-half (32-lane) sum; total lands at g==31 of each half
__device__ __forceinline__ float sum_half_last(float x) {
  x += dppz<0x111, 0xF>(x);   // row_shr:1
  x += dppz<0x112, 0xF>(x);   // row_shr:2
  x += dppz<0x114, 0xF>(x);   // row_shr:4
  x += dppz<0x118, 0xF>(x);   // row_shr:8
  x += dppz<0x142, 0xA>(x);   // row_bcast15 into rows 1&3
  return x;
}

__device__ __forceinline__ int rdlane(int v, int l) {
#if __has_builtin(__builtin_amdgcn_readlane)
  return __builtin_amdgcn_readlane(v, l);
#else
  return __shfl(v, l, 64);
#endif
}

// ===================== JAX threefry2x32, key(42) =====================
__device__ __forceinline__ uint32_t rotl_(uint32_t v, int s) { return (v << s) | (v >> (32 - s)); }

__device__ __forceinline__ uint32_t threefry_fold(uint32_t x0, uint32_t x1) {
  const uint32_t ks0 = 0u;
  const uint32_t ks1 = 42u;
  const uint32_t ks2 = 0x1BD11BDAu ^ 42u;
  uint32_t v0 = x0 + ks0;
  uint32_t v1 = x1 + ks1;
#define TF_R(rr) { v0 += v1; v1 = rotl_(v1, rr); v1 ^= v0; }
  TF_R(13) TF_R(15) TF_R(26) TF_R(6)
  v0 += ks1; v1 += ks2 + 1u;
  TF_R(17) TF_R(29) TF_R(16) TF_R(24)
  v0 += ks2; v1 += ks0 + 2u;
  TF_R(13) TF_R(15) TF_R(26) TF_R(6)
  v0 += ks0; v1 += ks1 + 3u;
  TF_R(17) TF_R(29) TF_R(16) TF_R(24)
  v0 += ks1; v1 += ks2 + 4u;
  TF_R(13) TF_R(15) TF_R(26) TF_R(6)
  v0 += ks2; v1 += ks0 + 5u;
#undef TF_R
  return v0 ^ v1;
}

__device__ __forceinline__ float jax_uniform01(uint32_t m) {
  uint32_t bits = threefry_fold(0u, m);
  return __uint_as_float((bits >> 9) | 0x3F800000u) - 1.0f;
}

__device__ __forceinline__ float load_a(const float* __restrict__ srow, int i) {
  float x = (i < ENS) ? srow[i] : PADV;
  return xla_logsigmoid(x);
}

// ===================== kernel 1: ckpt + logZ (+ optional pv stream) ================
__global__ __launch_bounds__(128) void k_scan1(const float* __restrict__ scores,
                                               float* __restrict__ ckpt,
                                               float* __restrict__ logZ,
                                               float* __restrict__ pvg,
                                               int wp) {
  __shared__ float abuf[2][2][64];
  int w = threadIdx.x >> 6;
  int lane = threadIdx.x & 63;
  int g = lane & 31, half = lane >> 5;
  int row = blockIdx.x * 2 + half;
  const float* srow = scores + (size_t)row * ENS;
  int role = (w + blockIdx.x) & 1;
  float* la = &abuf[w][half][0];

  if (role == 0) {
    float s = NEGC;
    #pragma unroll 1
    for (int seg = 15; seg >= 0; --seg) {
      if (seg <= 14) ckpt[((size_t)seg * BB + row) * 32 + g] = s;
      la[g] = load_a(srow, seg * 64 + g);
      la[32 + g] = load_a(srow, seg * 64 + 32 + g);
      // DS ops are wave-in-order; compiler inserts lgkm waits for read results.
      #pragma unroll 8
      for (int t = 63; t >= 0; --t) {
        float a = la[t];
        float prev = shup1(s);
        float sh = (g == 0) ? 0.0f : prev;
        float tv = a + sh;
        float amax = fmaxf(s, tv);
        float snew = amax + xla_log1pf(xla_expf(-fabsf(s - tv)));
        if (wp) {
          float pv = xla_expf(tv - snew);
          pv = fminf(fmaxf(pv, 0.0f), 1.0f);
          pvg[((size_t)row * NN + seg * 64 + t) * 32 + g] = pv;
        }
        s = snew;
      }
    }
  } else {
    float F = NEGC;
    #pragma unroll 1
    for (int seg = 0; seg <= 15; ++seg) {
      la[g] = load_a(srow, seg * 64 + g);
      la[32 + g] = load_a(srow, seg * 64 + 32 + g);
      #pragma unroll 8
      for (int t = 0; t < 64; ++t) {
        float a = la[t];
        float prev = shup1(F);
        float Fj = (g == 0) ? 0.0f : prev;
        F = fast_lae(F, a + Fj);
      }
    }
    if (g == 31) logZ[row] = F;
  }
}

// ===================== kernel 2 (fallback): producer + 2 scalar samplers + marg ====
__global__ __launch_bounds__(256) void k_fusedB(const float* __restrict__ scores,
                                                const float* __restrict__ ckpt,
                                                const float* __restrict__ logZ,
                                                float* __restrict__ margOut,
                                                uint32_t* __restrict__ bits) {
  __shared__ float pvring[2][2][64][32];   // 32768 B
  __shared__ float abuf[2][2][64];         // 1024 B
  int w = threadIdx.x >> 6;
  int lane = threadIdx.x & 63;
  int g = lane & 31, half = lane >> 5;
  int role = (w + blockIdx.x) & 3;   // 0 prod, 1 consA, 2 consB, 3 marg

  if (role == 0) {
    // ---------- producer: exact chain + pv ring ----------
    int row = blockIdx.x * 2 + half;
    const float* srow = scores + (size_t)row * ENS;
    float ck[15];
    #pragma unroll
    for (int q = 0; q < 15; ++q) ck[q] = ckpt[((size_t)q * BB + row) * 32 + g];
    #pragma unroll 1
    for (int ph = 0; ph <= 16; ++ph) {
      if (ph <= 15) {
        int seg = ph;
        float s = (seg == 15) ? NEGC : ck[0];
        #pragma unroll
        for (int q = 0; q <= 13; ++q) ck[q] = ck[q + 1];
        float* la = &abuf[ph & 1][half][0];
        float* rg = &pvring[ph & 1][half][0][0];
        la[g] = load_a(srow, seg * 64 + g);
        la[32 + g] = load_a(srow, seg * 64 + 32 + g);
        #pragma unroll 8
        for (int t = 63; t >= 0; --t) {
          float a = la[t];
          float prev = shup1(s);
          float sh = (g == 0) ? 0.0f : prev;
          float tv = a + sh;
          float amax = fmaxf(s, tv);
          float snew = amax + xla_log1pf(xla_expf(-fabsf(s - tv)));
          float pv = xla_expf(tv - snew);
          pv = fminf(fmaxf(pv, 0.0f), 1.0f);
          rg[t * 32 + g] = pv;
          s = snew;
        }
      }
      __syncthreads();
    }
  } else if (role == 1 || role == 2) {
    // ---------- scalar sampler, one wave per row ----------
    int rh = role - 1;
    int rowC = blockIdx.x * 2 + rh;
    int r = KK;
    #pragma unroll 1
    for (int ph = 0; ph <= 16; ++ph) {
      if (ph >= 1) {
        int seg = ph - 1;
        const float* rg = &pvring[(ph - 1) & 1][rh][0][0];
        float uv = jax_uniform01((uint32_t)((seg * 64 + lane) * BB + rowC));
        int pvv[64];
        #pragma unroll
        for (int t = 0; t < 64; ++t) pvv[t] = __float_as_int(rg[t * 32 + (lane & 31)]);
        uint32_t word = 0;
        #pragma unroll
        for (int t = 0; t < 64; ++t) {
          int rc = r < 1 ? 1 : (r > KK ? KK : r);
          int pb = rdlane(pvv[t], rc - 1);
          int ub = rdlane(__float_as_int(uv), t);
          // u,p >= 0: float u<p  <=>  unsigned-int bits compare (bit-exact)
          int inc = (r > 0) & ((uint32_t)ub < (uint32_t)pb);
          r -= inc;
          word |= ((uint32_t)inc) << (t & 31);
          if ((t & 31) == 31) {
            if (lane == 0) bits[rowC * 32 + seg * 2 + (t >> 5)] = word;
            word = 0;
          }
        }
      }
      __syncthreads();
    }
  } else {
    // ---------- marg: fast-S in VGPRs + no-max LSE centered on logZ ----------
    int row = blockIdx.x * 2 + half;
    const float* srow = scores + (size_t)row * ENS;
    float lz = logZ[row];
    float ck[15];
    #pragma unroll
    for (int q = 0; q < 15; ++q) ck[q] = ckpt[((size_t)q * BB + row) * 32 + g];
    float F = NEGC;
    #pragma unroll 1
    for (int ph = 0; ph <= 16; ++ph) {
      if (ph >= 1) {
        int seg = ph - 1;
        const float* la = &abuf[(ph - 1) & 1][half][0];
        float s = (seg == 15) ? NEGC : ck[0];
        #pragma unroll
        for (int q = 0; q <= 13; ++q) ck[q] = ck[q + 1];
        float sv[64];
        #pragma unroll
        for (int t = 63; t >= 0; --t) {
          float prevs = shup1(s);
          float sh = (g == 0) ? 0.0f : prevs;
          sv[t] = __shfl_xor(sh, 31, 64);     // lane g <- S[t+1][31-g]
          s = fast_lae(s, la[t] + sh);
        }
        #pragma unroll
        for (int t = 0; t < 64; ++t) {
          int i = seg * 64 + t;
          float a = la[t];
          float prevF = shup1(F);
          float Fj = (g == 0) ? 0.0f : prevF;
          float term = fexp2((Fj + sv[t] - lz) * L2E);
          float tot = sum_half_last(term);
          if (g == 31 && i < ENS)
            margOut[(size_t)row * ENS + i] = fexp2(a * L2E) * tot;
          F = fast_lae(F, a + Fj);
        }
      }
      __syncthreads();
    }
  }
}

// ===================== kernel 2 (big-ws): pv from global, no barriers ==============
__global__ __launch_bounds__(192) void k_procB(const float* __restrict__ scores,
                                               const float* __restrict__ ckpt,
                                               const float* __restrict__ logZ,
                                               const float* __restrict__ pvg,
                                               float* __restrict__ margOut,
                                               uint32_t* __restrict__ bits) {
  __shared__ float abufP[3][2][64];
  int w = threadIdx.x >> 6;
  int lane = threadIdx.x & 63;
  int g = lane & 31, half = lane >> 5;
  int role = (w + blockIdx.x) % 3;   // 0 consA, 1 consB, 2 marg

  if (role == 0 || role == 1) {
    int rowC = blockIdx.x * 2 + role;
    int r = KK;
    #pragma unroll 1
    for (int seg = 0; seg <= 15; ++seg) {
      float uv = jax_uniform01((uint32_t)((seg * 64 + lane) * BB + rowC));
      int pvv[64];
      #pragma unroll
      for (int t = 0; t < 64; ++t)
        pvv[t] = __float_as_int(pvg[((size_t)rowC * NN + seg * 64 + t) * 32 + (lane & 31)]);
      uint32_t word = 0;
      #pragma unroll
      for (int t = 0; t < 64; ++t) {
        int rc = r < 1 ? 1 : (r > KK ? KK : r);
        int pb = rdlane(pvv[t], rc - 1);
        int ub = rdlane(__float_as_int(uv), t);
        int inc = (r > 0) & ((uint32_t)ub < (uint32_t)pb);
        r -= inc;
        word |= ((uint32_t)inc) << (t & 31);
        if ((t & 31) == 31) {
          if (lane == 0) bits[rowC * 32 + seg * 2 + (t >> 5)] = word;
          word = 0;
        }
      }
    }
  } else {
    int row = blockIdx.x * 2 + half;
    const float* srow = scores + (size_t)row * ENS;
    float lz = logZ[row];
    float ck[15];
    #pragma unroll
    for (int q = 0; q < 15; ++q) ck[q] = ckpt[((size_t)q * BB + row) * 32 + g];
    float* la = &abufP[w][half][0];
    float F = NEGC;
    #pragma unroll 1
    for (int seg = 0; seg <= 15; ++seg) {
      la[g] = load_a(srow, seg * 64 + g);
      la[32 + g] = load_a(srow, seg * 64 + 32 + g);
      float s = (seg == 15) ? NEGC : ck[0];
      #pragma unroll
      for (int q = 0; q <= 13; ++q) ck[q] = ck[q + 1];
      float sv[64];
      #pragma unroll
      for (int t = 63; t >= 0; --t) {
        float prevs = shup1(s);
        float sh = (g == 0) ? 0.0f : prevs;
        sv[t] = __shfl_xor(sh, 31, 64);
        s = fast_lae(s, la[t] + sh);
      }
      #pragma unroll
      for (int t = 0; t < 64; ++t) {
        int i = seg * 64 + t;
        float a = la[t];
        float prevF = shup1(F);
        float Fj = (g == 0) ? 0.0f : prevF;
        float term = fexp2((Fj + sv[t] - lz) * L2E);
        float tot = sum_half_last(term);
        if (g == 31 && i < ENS)
          margOut[(size_t)row * ENS + i] = fexp2(a * L2E) * tot;
        F = fast_lae(F, a + Fj);
      }
    }
  }
}

// samples = (bit - marg) + marg
__global__ __launch_bounds__(256) void k_final(const float* __restrict__ margOut,
                                               const uint32_t* __restrict__ bits,
                                               float* __restrict__ out) {
  int idx = blockIdx.x * 256 + threadIdx.x;
  if (idx >= BB * ENS) return;
  int row = idx / ENS;
  int i = idx - row * ENS;
  float marg = margOut[idx];
  uint32_t wbits = bits[row * 32 + (i >> 5)];
  float bit = (float)((wbits >> (i & 31)) & 1u);
  out[idx] = (bit - marg) + marg;
}

extern "C" void kernel_launch(void* const* d_in, const int* in_sizes, int n_in,
                              void* d_out, int out_size, void* d_ws, size_t ws_size,
                              hipStream_t stream) {
  const float* scores = (const float*)d_in[0];
  float* outbuf = (float*)d_out;
  float* margOut = outbuf + (size_t)BB * ENS;

  float* ws = (float*)d_ws;
  float* ckpt = ws;                               // 15*BB*32 floats
  float* logZ = ckpt + (size_t)15 * BB * 32;      // BB floats
  uint32_t* bits = (uint32_t*)(logZ + BB);        // BB*32 words
  float* pvg = (float*)(bits + (size_t)BB * 32);  // BB*NN*32 floats (big path only)
  (void)in_sizes; (void)n_in; (void)out_size;

  size_t need_big = ((size_t)15 * BB * 32 + BB) * 4 + (size_t)BB * 32 * 4
                  + (size_t)BB * NN * 32 * 4;
  int big = (ws_size >= need_big) ? 1 : 0;

  hipLaunchKernelGGL(k_scan1, dim3(BB / 2), dim3(128), 0, stream,
                     scores, ckpt, logZ, pvg, big);
  if (big) {
    hipLaunchKernelGGL(k_procB, dim3(BB / 2), dim3(192), 0, stream,
                       scores, ckpt, logZ, pvg, margOut, bits);
  } else {
    hipLaunchKernelGGL(k_fusedB, dim3(BB / 2), dim3(256), 0, stream,
                       scores, ckpt, logZ, margOut, bits);
  }
  hipLaunchKernelGGL(k_final, dim3((BB * ENS + 255) / 256), dim3(256), 0, stream,
                     margOut, bits, outbuf);
}